// Round 12
// baseline (473.213 us; speedup 1.0000x reference)
//
#include <hip/hip_runtime.h>
#include <math.h>

#define N_NODES 50000
#define N_EDGES 800000
#define ETOT (N_EDGES + N_NODES)
#define EB ((ETOT + 255) / 256)
#define F_IN 128
#define HD 64
#define NHEAD 4
#define HC 256
#define NGRAPH 512
#define NOUT 64
#define LN_EPS 1e-5f

typedef __attribute__((ext_vector_type(8))) short bf16x8;
typedef __attribute__((ext_vector_type(4))) float f32x4;
typedef __attribute__((ext_vector_type(2))) float f32x2;

__device__ __forceinline__ float wave_sum(float v) {
#pragma unroll
    for (int m = 1; m < 64; m <<= 1) v += __shfl_xor(v, m, 64);
    return v;
}
__device__ __forceinline__ float wave_max(float v) {
#pragma unroll
    for (int m = 1; m < 64; m <<= 1) v = fmaxf(v, __shfl_xor(v, m, 64));
    return v;
}
__device__ __forceinline__ float red16(float v) {
    v += __shfl_xor(v, 1, 64);
    v += __shfl_xor(v, 2, 64);
    v += __shfl_xor(v, 4, 64);
    v += __shfl_xor(v, 8, 64);
    return v;
}
__device__ __forceinline__ float gelu_exact(float x) {
    return 0.5f * x * (1.0f + erff(x * 0.70710678118654752f));
}
__device__ __forceinline__ unsigned short f2bf(float x) {
    unsigned int u = __float_as_uint(x);
    return (unsigned short)((u + 0x7fffu + ((u >> 16) & 1u)) >> 16);
}
__device__ __forceinline__ float bf2f(unsigned short u) {
    return __uint_as_float(((unsigned int)u) << 16);
}

// ---------------- merged: degree count + weight packing + u-vector prep ----------------
// blocks [0,EB): count ; [EB,EB+48): inW ; [+48,+112): W0 (pi perm) ; [+112,+368): W1 ; +368: prep_u
__global__ void k_prep_all(const int* __restrict__ ei, const float* __restrict__ inW,
                           const float* __restrict__ W0, const float* __restrict__ W1,
                           const float* __restrict__ as0, const float* __restrict__ ad0,
                           int* __restrict__ deg,
                           unsigned short* __restrict__ inWpk, unsigned short* __restrict__ W0pk,
                           unsigned short* __restrict__ W1pk, float* __restrict__ us,
                           float* __restrict__ ud) {
    int b = blockIdx.x;
    if (b < EB) {
        int t = b * 256 + threadIdx.x;
        if (t >= ETOT) return;
        int dst = (t < N_EDGES) ? ei[N_EDGES + t] : (t - N_EDGES);
        atomicAdd(deg + dst, 1);
        return;
    }
    b -= EB;
    if (b < 48) {
        int tid = b * 256 + threadIdx.x;
        int i = tid & 7, l = (tid >> 3) & 63, t2 = tid >> 9;
        int nb = t2 % 4, kt = t2 / 4;
        int k = kt * 32 + ((l >> 4) << 3) + i;
        int n = nb * 16 + (l & 15);
        inWpk[tid] = f2bf(inW[k * 64 + n]);
    } else if (b < 112) {
        int tid = (b - 48) * 256 + threadIdx.x;
        int i = tid & 7, l = (tid >> 3) & 63, t2 = tid >> 9;
        int nb = t2 % 16, kt = t2 / 16;
        int q = kt * 32 + ((l >> 4) << 3) + i;   // packed row position
        int k = 16 * (q & 3) + (q >> 2);         // canonical W0 row (pi perm)
        int n = nb * 16 + (l & 15);
        W0pk[tid] = f2bf(W0[k * 256 + n]);
    } else if (b < 368) {
        int tid = (b - 112) * 256 + threadIdx.x;
        int i = tid & 7, l = (tid >> 3) & 63, t2 = tid >> 9;
        int nb = t2 % 16, kt = t2 / 16;
        int k = kt * 32 + ((l >> 4) << 3) + i;
        int n = nb * 16 + (l & 15);
        W1pk[tid] = f2bf(W1[k * 256 + n]);
    } else {
        int t = threadIdx.x;
        int h = t >> 6, k2 = t & 63;
        float ss = 0.f, dd = 0.f;
        for (int c = 0; c < 64; c++) {
            float w = W0[k2 * 256 + h * 64 + c];
            ss += w * as0[h * 64 + c];
            dd += w * ad0[h * 64 + c];
        }
        us[t] = ss;
        ud[t] = dd;
    }
}

// ---------------- fast single-block scan: thread-serial sums + one 1024-wide scan ----------------
__global__ void k_scan(const int* __restrict__ deg, int* __restrict__ rowptr,
                       int* __restrict__ cursor) {
    const int PER = 49;  // 1024 * 49 >= N_NODES
    __shared__ int wsum[16];
    int tid = threadIdx.x, wid = tid >> 6, lane = tid & 63;
    int base = tid * PER;
    int sum = 0;
#pragma unroll 7
    for (int i = 0; i < PER; i++) {
        int idx = base + i;
        if (idx < N_NODES) sum += deg[idx];
    }
    int incl = sum;
#pragma unroll
    for (int off = 1; off < 64; off <<= 1) {
        int t = __shfl_up(incl, off, 64);
        if (lane >= off) incl += t;
    }
    if (lane == 63) wsum[wid] = incl;
    __syncthreads();
    if (wid == 0) {
        int wv = (lane < 16) ? wsum[lane] : 0;
        int wincl = wv;
#pragma unroll
        for (int off = 1; off < 16; off <<= 1) {
            int t = __shfl_up(wincl, off, 64);
            if (lane >= off) wincl += t;
        }
        if (lane < 16) wsum[lane] = wincl - wv;  // exclusive wave offset
    }
    __syncthreads();
    int run = wsum[wid] + incl - sum;  // exclusive prefix for this thread
    if (tid == 0) rowptr[0] = 0;
#pragma unroll 7
    for (int i = 0; i < PER; i++) {
        int idx = base + i;
        if (idx < N_NODES) {
            int v = deg[idx];
            cursor[idx] = run;
            run += v;
            rowptr[idx + 1] = run;
        }
    }
}

__global__ void k_fill(const int* __restrict__ ei, int* __restrict__ cursor,
                       int* __restrict__ csr) {
    int t = blockIdx.x * blockDim.x + threadIdx.x;
    if (t >= ETOT) return;
    int src, dst;
    if (t < N_EDGES) { src = ei[t]; dst = ei[N_EDGES + t]; }
    else             { src = t - N_EDGES; dst = src; }
    int p = atomicAdd(cursor + dst, 1);
    csr[p] = src;
}

// ---------------- input projection (MFMA), direct f32 reads, fp8 out, fused logits ----------------
__global__ void k_proj_in_mma(const float* __restrict__ x, const int* __restrict__ gid,
                              const float* __restrict__ gt,
                              const unsigned short* __restrict__ Wpk,
                              const float* __restrict__ inb, const float* __restrict__ lng,
                              const float* __restrict__ lnb, const float* __restrict__ us,
                              const float* __restrict__ ud, unsigned int* __restrict__ h08,
                              float* __restrict__ als0, float* __restrict__ ald0) {
    int wid = threadIdx.x >> 6, lane = threadIdx.x & 63;
    int m0 = blockIdx.x * 64 + wid * 16;
    if (m0 >= N_NODES) return;
    int g16 = lane >> 4, c16 = lane & 15;
    int row_a = m0 + c16;
    int g = gid[row_a];
    f32x4 acc[4] = {{0,0,0,0},{0,0,0,0},{0,0,0,0},{0,0,0,0}};
#pragma unroll
    for (int kt = 0; kt < 6; kt++) {
        const float* src = (kt < 4) ? (x + (size_t)row_a * F_IN + kt * 32 + g16 * 8)
                                    : (gt + (size_t)g * HD + (kt - 4) * 32 + g16 * 8);
        float4 f0 = *(const float4*)(src);
        float4 f1 = *(const float4*)(src + 4);
        bf16x8 a;
        a[0] = (short)f2bf(f0.x); a[1] = (short)f2bf(f0.y);
        a[2] = (short)f2bf(f0.z); a[3] = (short)f2bf(f0.w);
        a[4] = (short)f2bf(f1.x); a[5] = (short)f2bf(f1.y);
        a[6] = (short)f2bf(f1.z); a[7] = (short)f2bf(f1.w);
#pragma unroll
        for (int nt = 0; nt < 4; nt++) {
            bf16x8 b = *(const bf16x8*)(Wpk + (((kt * 4 + nt) * 64 + lane) << 3));
            acc[nt] = __builtin_amdgcn_mfma_f32_16x16x32_bf16(a, b, acc[nt], 0, 0, 0);
        }
    }
    float bv[4], gv[4], bb[4];
    float usl[4][4], udl[4][4];
#pragma unroll
    for (int nt = 0; nt < 4; nt++) {
        int c = nt * 16 + c16;
        bv[nt] = inb[c]; gv[nt] = lng[c]; bb[nt] = lnb[c];
#pragma unroll
        for (int h = 0; h < 4; h++) {
            usl[h][nt] = us[h * 64 + c];
            udl[h][nt] = ud[h * 64 + c];
        }
    }
#pragma unroll
    for (int j = 0; j < 4; j++) {
        float d[4], s = 0.f;
#pragma unroll
        for (int nt = 0; nt < 4; nt++) { d[nt] = acc[nt][j] + bv[nt]; s += d[nt]; }
        float mu = red16(s) * (1.0f / 64.0f);
        float v = 0.f;
#pragma unroll
        for (int nt = 0; nt < 4; nt++) { d[nt] -= mu; v += d[nt] * d[nt]; }
        float r = rsqrtf(red16(v) * (1.0f / 64.0f) + LN_EPS);
        int row = m0 + g16 * 4 + j;
        float y0 = gelu_exact(d[0] * r * gv[0] + bb[0]);
        float y1 = gelu_exact(d[1] * r * gv[1] + bb[1]);
        float y2 = gelu_exact(d[2] * r * gv[2] + bb[2]);
        float y3 = gelu_exact(d[3] * r * gv[3] + bb[3]);
        int u = __builtin_amdgcn_cvt_pk_fp8_f32(y0, y1, 0, false);
        u = __builtin_amdgcn_cvt_pk_fp8_f32(y2, y3, u, true);
        h08[(size_t)row * 16 + c16] = (unsigned int)u;
        float ps0 = y0 * usl[0][0] + y1 * usl[0][1] + y2 * usl[0][2] + y3 * usl[0][3];
        float ps1 = y0 * usl[1][0] + y1 * usl[1][1] + y2 * usl[1][2] + y3 * usl[1][3];
        float ps2 = y0 * usl[2][0] + y1 * usl[2][1] + y2 * usl[2][2] + y3 * usl[2][3];
        float ps3 = y0 * usl[3][0] + y1 * usl[3][1] + y2 * usl[3][2] + y3 * usl[3][3];
        float pd0 = y0 * udl[0][0] + y1 * udl[0][1] + y2 * udl[0][2] + y3 * udl[0][3];
        float pd1 = y0 * udl[1][0] + y1 * udl[1][1] + y2 * udl[1][2] + y3 * udl[1][3];
        float pd2 = y0 * udl[2][0] + y1 * udl[2][1] + y2 * udl[2][2] + y3 * udl[2][3];
        float pd3 = y0 * udl[3][0] + y1 * udl[3][1] + y2 * udl[3][2] + y3 * udl[3][3];
        ps0 = red16(ps0); ps1 = red16(ps1); ps2 = red16(ps2); ps3 = red16(ps3);
        pd0 = red16(pd0); pd1 = red16(pd1); pd2 = red16(pd2); pd3 = red16(pd3);
        if (c16 == 0) {
            float4 s4 = {ps0, ps1, ps2, ps3};
            float4 d4 = {pd0, pd1, pd2, pd3};
            ((float4*)als0)[row] = s4;
            ((float4*)ald0)[row] = d4;
        }
    }
}

// ---------------- layer-0 aggregation over fp8 h0 (64B/edge), single-pass, unroll-2 ----------------
__global__ void k_agg0(const int* __restrict__ rowptr, const int* __restrict__ csr,
                       const unsigned int* __restrict__ h08, const float* __restrict__ als,
                       const float* __restrict__ ald, unsigned short* __restrict__ aggbf) {
    __shared__ float4 lacc[2][64];
    __shared__ float lss[2][4];
    int wid = threadIdx.x >> 6, lane = threadIdx.x & 63;
    int nloc = wid >> 1, half = wid & 1;
    int node = blockIdx.x * 2 + nloc;
    int start = rowptr[node], end = rowptr[node + 1];
    int g = lane >> 4, l16 = lane & 15;
    float4 adv = ((const float4*)ald)[node];
    int cntE = end - start;
    int mid = start + ((cntE + 1) >> 1);
    int k0 = half ? mid : start;
    int k1 = half ? end : mid;
    float a00 = 0, a01 = 0, a02 = 0, a03 = 0;
    float a10 = 0, a11 = 0, a12 = 0, a13 = 0;
    float a20 = 0, a21 = 0, a22 = 0, a23 = 0;
    float a30 = 0, a31 = 0, a32 = 0, a33 = 0;
    float s0 = 0, s1 = 0, s2 = 0, s3 = 0;
    const float4* als4 = (const float4*)als;
    for (int kb = k0; kb < k1; kb += 8) {
        int eA = kb + g, eB = kb + 4 + g;
        int cA = (eA < k1) ? eA : (k1 - 1);
        int cB = (eB < k1) ? eB : (k1 - 1);
        int snA = csr[cA], snB = csr[cB];
        float4 avA = als4[snA], avB = als4[snB];
        unsigned int uA = h08[(size_t)snA * 16 + l16];
        unsigned int uB = h08[(size_t)snB * 16 + l16];
        float eA0 = avA.x + adv.x; eA0 = fmaxf(eA0, 0.2f * eA0);
        float eA1 = avA.y + adv.y; eA1 = fmaxf(eA1, 0.2f * eA1);
        float eA2 = avA.z + adv.z; eA2 = fmaxf(eA2, 0.2f * eA2);
        float eA3 = avA.w + adv.w; eA3 = fmaxf(eA3, 0.2f * eA3);
        float wA0 = __expf(eA0), wA1 = __expf(eA1), wA2 = __expf(eA2), wA3 = __expf(eA3);
        if (eA >= k1) { wA0 = 0.f; wA1 = 0.f; wA2 = 0.f; wA3 = 0.f; }
        f32x2 loA = __builtin_amdgcn_cvt_pk_f32_fp8((int)uA, false);
        f32x2 hiA = __builtin_amdgcn_cvt_pk_f32_fp8((int)uA, true);
        s0 += wA0; s1 += wA1; s2 += wA2; s3 += wA3;
        float x0 = loA.x, x1 = loA.y, x2 = hiA.x, x3 = hiA.y;
        a00 += wA0 * x0; a01 += wA0 * x1; a02 += wA0 * x2; a03 += wA0 * x3;
        a10 += wA1 * x0; a11 += wA1 * x1; a12 += wA1 * x2; a13 += wA1 * x3;
        a20 += wA2 * x0; a21 += wA2 * x1; a22 += wA2 * x2; a23 += wA2 * x3;
        a30 += wA3 * x0; a31 += wA3 * x1; a32 += wA3 * x2; a33 += wA3 * x3;
        float eB0 = avB.x + adv.x; eB0 = fmaxf(eB0, 0.2f * eB0);
        float eB1 = avB.y + adv.y; eB1 = fmaxf(eB1, 0.2f * eB1);
        float eB2 = avB.z + adv.z; eB2 = fmaxf(eB2, 0.2f * eB2);
        float eB3 = avB.w + adv.w; eB3 = fmaxf(eB3, 0.2f * eB3);
        float wB0 = __expf(eB0), wB1 = __expf(eB1), wB2 = __expf(eB2), wB3 = __expf(eB3);
        if (eB >= k1) { wB0 = 0.f; wB1 = 0.f; wB2 = 0.f; wB3 = 0.f; }
        f32x2 loB = __builtin_amdgcn_cvt_pk_f32_fp8((int)uB, false);
        f32x2 hiB = __builtin_amdgcn_cvt_pk_f32_fp8((int)uB, true);
        s0 += wB0; s1 += wB1; s2 += wB2; s3 += wB3;
        float z0 = loB.x, z1 = loB.y, z2 = hiB.x, z3 = hiB.y;
        a00 += wB0 * z0; a01 += wB0 * z1; a02 += wB0 * z2; a03 += wB0 * z3;
        a10 += wB1 * z0; a11 += wB1 * z1; a12 += wB1 * z2; a13 += wB1 * z3;
        a20 += wB2 * z0; a21 += wB2 * z1; a22 += wB2 * z2; a23 += wB2 * z3;
        a30 += wB3 * z0; a31 += wB3 * z1; a32 += wB3 * z2; a33 += wB3 * z3;
    }
#define RED2(v) v += __shfl_xor(v, 16, 64); v += __shfl_xor(v, 32, 64)
    RED2(a00); RED2(a01); RED2(a02); RED2(a03);
    RED2(a10); RED2(a11); RED2(a12); RED2(a13);
    RED2(a20); RED2(a21); RED2(a22); RED2(a23);
    RED2(a30); RED2(a31); RED2(a32); RED2(a33);
    RED2(s0);  RED2(s1);  RED2(s2);  RED2(s3);
#undef RED2
    if (half) {
        float o0 = (g == 0) ? a00 : (g == 1) ? a10 : (g == 2) ? a20 : a30;
        float o1 = (g == 0) ? a01 : (g == 1) ? a11 : (g == 2) ? a21 : a31;
        float o2 = (g == 0) ? a02 : (g == 1) ? a12 : (g == 2) ? a22 : a32;
        float o3 = (g == 0) ? a03 : (g == 1) ? a13 : (g == 2) ? a23 : a33;
        float4 o = {o0, o1, o2, o3};
        lacc[nloc][lane] = o;
        if (lane < 4) {
            float sv = (lane == 0) ? s0 : (lane == 1) ? s1 : (lane == 2) ? s2 : s3;
            lss[nloc][lane] = sv;
        }
    }
    __syncthreads();
    if (!half) {
        float4 p0 = lacc[nloc][0 + l16];
        float4 p1 = lacc[nloc][16 + l16];
        float4 p2 = lacc[nloc][32 + l16];
        float4 p3 = lacc[nloc][48 + l16];
        a00 += p0.x; a01 += p0.y; a02 += p0.z; a03 += p0.w;
        a10 += p1.x; a11 += p1.y; a12 += p1.z; a13 += p1.w;
        a20 += p2.x; a21 += p2.y; a22 += p2.z; a23 += p2.w;
        a30 += p3.x; a31 += p3.y; a32 += p3.z; a33 += p3.w;
        s0 += lss[nloc][0]; s1 += lss[nloc][1];
        s2 += lss[nloc][2]; s3 += lss[nloc][3];
        float o0 = (g == 0) ? a00 : (g == 1) ? a10 : (g == 2) ? a20 : a30;
        float o1 = (g == 0) ? a01 : (g == 1) ? a11 : (g == 2) ? a21 : a31;
        float o2 = (g == 0) ? a02 : (g == 1) ? a12 : (g == 2) ? a22 : a32;
        float o3 = (g == 0) ? a03 : (g == 1) ? a13 : (g == 2) ? a23 : a33;
        float sg = (g == 0) ? s0 : (g == 1) ? s1 : (g == 2) ? s2 : s3;
        float inv = 1.0f / (sg + 1e-16f);
        ushort4 o = {f2bf(o0 * inv), f2bf(o1 * inv), f2bf(o2 * inv), f2bf(o3 * inv)};
        ((ushort4*)aggbf)[(size_t)node * 64 + lane] = o;
    }
}

// ---------------- post-agg block-diagonal GEMM (64->256 per head) + bias + LN + GELU ----------------
__global__ void k_postgemm0(const unsigned short* __restrict__ A,
                            const unsigned short* __restrict__ Wpk,
                            const float* __restrict__ bias, const float* __restrict__ lng,
                            const float* __restrict__ lnb, unsigned short* __restrict__ h1bf) {
    int wid = threadIdx.x >> 6, lane = threadIdx.x & 63;
    int m0 = blockIdx.x * 64 + wid * 16;
    if (m0 >= N_NODES) return;
    int g16 = lane >> 4, c16 = lane & 15;
    f32x4 acc[16] = {};
#pragma unroll
    for (int h = 0; h < 4; h++) {
#pragma unroll
        for (int kt = 0; kt < 2; kt++) {
            bf16x8 a = *(const bf16x8*)(A + (size_t)(m0 + c16) * 256 + h * 64 + kt * 32 + g16 * 8);
#pragma unroll
            for (int nt = 0; nt < 4; nt++) {
                bf16x8 b = *(const bf16x8*)(Wpk + (((kt * 16 + h * 4 + nt) * 64 + lane) << 3));
                acc[h * 4 + nt] = __builtin_amdgcn_mfma_f32_16x16x32_bf16(a, b, acc[h * 4 + nt], 0, 0, 0);
            }
        }
    }
    float bv[16], gv[16], bb[16];
#pragma unroll
    for (int q = 0; q < 16; q++) {
        int c = q * 16 + c16;
        bv[q] = bias[c]; gv[q] = lng[c]; bb[q] = lnb[c];
    }
#pragma unroll
    for (int j = 0; j < 4; j++) {
        float d[16], ssum = 0.f;
#pragma unroll
        for (int q = 0; q < 16; q++) { d[q] = acc[q][j] + bv[q]; ssum += d[q]; }
        float mu = red16(ssum) * (1.0f / 256.0f);
        float v = 0.f;
#pragma unroll
        for (int q = 0; q < 16; q++) { d[q] -= mu; v += d[q] * d[q]; }
        float r = rsqrtf(red16(v) * (1.0f / 256.0f) + LN_EPS);
        int row = m0 + g16 * 4 + j;
#pragma unroll
        for (int q = 0; q < 16; q++) {
            float y = gelu_exact(d[q] * r * gv[q] + bb[q]);
            h1bf[(size_t)row * 256 + q * 16 + c16] = f2bf(y);
        }
    }
}

// ---------------- GAT projection (MFMA): xl(fp8, permuted) = A@W1, + layer-1 logits ----------------
__global__ void k_proj_mma(const unsigned short* __restrict__ A,
                           const unsigned short* __restrict__ Wpk,
                           const float* __restrict__ as_, const float* __restrict__ ad_,
                           unsigned int* __restrict__ xl8, float* __restrict__ als,
                           float* __restrict__ ald) {
    int wid = threadIdx.x >> 6, lane = threadIdx.x & 63;  // wid = head
    int m0 = blockIdx.x * 16;
    int g16 = lane >> 4, c16 = lane & 15;
    f32x4 acc[4] = {{0,0,0,0},{0,0,0,0},{0,0,0,0},{0,0,0,0}};
#pragma unroll
    for (int kt = 0; kt < 8; kt++) {
        bf16x8 a = *(const bf16x8*)(A + (size_t)(m0 + c16) * 256 + kt * 32 + g16 * 8);
#pragma unroll
        for (int nt = 0; nt < 4; nt++) {
            bf16x8 b = *(const bf16x8*)(Wpk + (((kt * 16 + wid * 4 + nt) * 64 + lane) << 3));
            acc[nt] = __builtin_amdgcn_mfma_f32_16x16x32_bf16(a, b, acc[nt], 0, 0, 0);
        }
    }
    float asv[4], adv[4];
#pragma unroll
    for (int nt = 0; nt < 4; nt++) {
        int c = wid * 64 + nt * 16 + c16;
        asv[nt] = as_[c]; adv[nt] = ad_[c];
    }
#pragma unroll
    for (int j = 0; j < 4; j++) {
        int row = m0 + g16 * 4 + j;
        float v0 = acc[0][j], v1 = acc[1][j], v2 = acc[2][j], v3 = acc[3][j];
        int u = __builtin_amdgcn_cvt_pk_fp8_f32(v0, v1, 0, false);
        u = __builtin_amdgcn_cvt_pk_fp8_f32(v2, v3, u, true);
        xl8[(size_t)row * 64 + wid * 16 + c16] = (unsigned int)u;
        float ps = v0 * asv[0] + v1 * asv[1] + v2 * asv[2] + v3 * asv[3];
        float pd = v0 * adv[0] + v1 * adv[1] + v2 * adv[2] + v3 * adv[3];
        ps = red16(ps); pd = red16(pd);
        if (c16 == 0) { als[row * 4 + wid] = ps; ald[row * 4 + wid] = pd; }
    }
}

// ---------------- layer-1 aggregation (256B/edge fp8), 2 waves/node, unroll-4, fused epilogue ----------------
__global__ void k_agg1(const int* __restrict__ rowptr, const int* __restrict__ csr,
                       const unsigned int* __restrict__ xl8, const float* __restrict__ als,
                       const float* __restrict__ ald, const float* __restrict__ bias,
                       const float* __restrict__ lng, const float* __restrict__ lnb,
                       const unsigned short* __restrict__ identity_bf,
                       const int* __restrict__ batch, float* __restrict__ pooled,
                       int* __restrict__ cnt) {
    __shared__ float4 lacc[2][64];
    __shared__ float lss[2][64];
    __shared__ float4 lyout[2][64];
    __shared__ int lbatch[2];
    int wid = threadIdx.x >> 6, lane = threadIdx.x & 63;
    int nloc = wid >> 1, half = wid & 1;
    int node = blockIdx.x * 2 + nloc;
    int start = rowptr[node], end = rowptr[node + 1];
    int head = lane >> 4, c16 = lane & 15;
    int fb = head * 64 + c16;
    float adh = ald[node * 4 + head];
    int cntE = end - start;
    int mid = start + ((cntE + 1) >> 1);
    int k0 = half ? mid : start;
    int k1 = half ? end : mid;
    float4 acc = {0.f, 0.f, 0.f, 0.f};
    float s = 0.f;
    int k = k0;
    for (; k + 4 <= k1; k += 4) {
        int sn0 = csr[k], sn1 = csr[k + 1], sn2 = csr[k + 2], sn3 = csr[k + 3];
        float e0 = als[sn0 * 4 + head] + adh;
        float e1 = als[sn1 * 4 + head] + adh;
        float e2 = als[sn2 * 4 + head] + adh;
        float e3 = als[sn3 * 4 + head] + adh;
        unsigned int u0 = xl8[(size_t)sn0 * 64 + lane];
        unsigned int u1 = xl8[(size_t)sn1 * 64 + lane];
        unsigned int u2 = xl8[(size_t)sn2 * 64 + lane];
        unsigned int u3 = xl8[(size_t)sn3 * 64 + lane];
        e0 = fmaxf(e0, 0.2f * e0); e1 = fmaxf(e1, 0.2f * e1);
        e2 = fmaxf(e2, 0.2f * e2); e3 = fmaxf(e3, 0.2f * e3);
        float a0 = __expf(e0), a1 = __expf(e1), a2 = __expf(e2), a3 = __expf(e3);
        s += a0 + a1 + a2 + a3;
        f32x2 lo0 = __builtin_amdgcn_cvt_pk_f32_fp8((int)u0, false);
        f32x2 hi0 = __builtin_amdgcn_cvt_pk_f32_fp8((int)u0, true);
        f32x2 lo1 = __builtin_amdgcn_cvt_pk_f32_fp8((int)u1, false);
        f32x2 hi1 = __builtin_amdgcn_cvt_pk_f32_fp8((int)u1, true);
        f32x2 lo2 = __builtin_amdgcn_cvt_pk_f32_fp8((int)u2, false);
        f32x2 hi2 = __builtin_amdgcn_cvt_pk_f32_fp8((int)u2, true);
        f32x2 lo3 = __builtin_amdgcn_cvt_pk_f32_fp8((int)u3, false);
        f32x2 hi3 = __builtin_amdgcn_cvt_pk_f32_fp8((int)u3, true);
        acc.x += a0 * lo0.x + a1 * lo1.x + a2 * lo2.x + a3 * lo3.x;
        acc.y += a0 * lo0.y + a1 * lo1.y + a2 * lo2.y + a3 * lo3.y;
        acc.z += a0 * hi0.x + a1 * hi1.x + a2 * hi2.x + a3 * hi3.x;
        acc.w += a0 * hi0.y + a1 * hi1.y + a2 * hi2.y + a3 * hi3.y;
    }
    for (; k < k1; k++) {
        int sn = csr[k];
        float e = als[sn * 4 + head] + adh;
        e = fmaxf(e, 0.2f * e);
        float a = __expf(e);
        s += a;
        unsigned int u = xl8[(size_t)sn * 64 + lane];
        f32x2 lo = __builtin_amdgcn_cvt_pk_f32_fp8((int)u, false);
        f32x2 hi = __builtin_amdgcn_cvt_pk_f32_fp8((int)u, true);
        acc.x += a * lo.x; acc.y += a * lo.y;
        acc.z += a * hi.x; acc.w += a * hi.y;
    }
    if (half) { lacc[nloc][lane] = acc; lss[nloc][lane] = s; }
    __syncthreads();
    if (!half) {
        float4 p = lacc[nloc][lane];
        acc.x += p.x; acc.y += p.y; acc.z += p.z; acc.w += p.w;
        s += lss[nloc][lane];
        float inv = 1.0f / (s + 1e-16f);
        acc.x = acc.x * inv + bias[fb];
        acc.y = acc.y * inv + bias[fb + 16];
        acc.z = acc.z * inv + bias[fb + 32];
        acc.w = acc.w * inv + bias[fb + 48];
        float mu = wave_sum(acc.x + acc.y + acc.z + acc.w) * (1.0f / 256.0f);
        float dx = acc.x - mu, dy = acc.y - mu, dz = acc.z - mu, dw = acc.w - mu;
        float var = wave_sum(dx * dx + dy * dy + dz * dz + dw * dw) * (1.0f / 256.0f);
        float r = rsqrtf(var + LN_EPS);
        float g0v = lng[fb], g1v = lng[fb + 16], g2v = lng[fb + 32], g3v = lng[fb + 48];
        float b0v = lnb[fb], b1v = lnb[fb + 16], b2v = lnb[fb + 32], b3v = lnb[fb + 48];
        const unsigned short* idp = identity_bf + (size_t)node * 256 + fb;
        float4 y;
        y.x = gelu_exact(dx * r * g0v + b0v) + bf2f(idp[0]);
        y.y = gelu_exact(dy * r * g1v + b1v) + bf2f(idp[16]);
        y.z = gelu_exact(dz * r * g2v + b2v) + bf2f(idp[32]);
        y.w = gelu_exact(dw * r * g3v + b3v) + bf2f(idp[48]);
        lyout[nloc][lane] = y;
        if (lane == 0) lbatch[nloc] = batch[node];
    }
    __syncthreads();
    if (wid == 0) {
        int g0 = lbatch[0], g1 = lbatch[1];
        float4 a = lyout[0][lane], b = lyout[1][lane];
        float* p0 = pooled + (size_t)g0 * 256 + fb;
        if (g0 == g1) {
            atomicAdd(p0 +  0, a.x + b.x); atomicAdd(p0 + 16, a.y + b.y);
            atomicAdd(p0 + 32, a.z + b.z); atomicAdd(p0 + 48, a.w + b.w);
            if (lane == 0) atomicAdd(cnt + g0, 2);
        } else {
            float* p1 = pooled + (size_t)g1 * 256 + fb;
            atomicAdd(p0 +  0, a.x); atomicAdd(p0 + 16, a.y);
            atomicAdd(p0 + 32, a.z); atomicAdd(p0 + 48, a.w);
            atomicAdd(p1 +  0, b.x); atomicAdd(p1 + 16, b.y);
            atomicAdd(p1 + 32, b.z); atomicAdd(p1 + 48, b.w);
            if (lane == 0) { atomicAdd(cnt + g0, 1); atomicAdd(cnt + g1, 1); }
        }
    }
}

// ---------------- pooled MLP + log_softmax: one wave per graph ----------------
__global__ void k_final(const float* __restrict__ pooled, const int* __restrict__ cnt,
                        const float* __restrict__ fc1W, const float* __restrict__ fc1b,
                        const float* __restrict__ fc2W, const float* __restrict__ fc2b,
                        float* __restrict__ out) {
    __shared__ float prow[4][256];
    __shared__ float zrow[4][64];
    int wid = threadIdx.x >> 6, lane = threadIdx.x & 63;
    int g = blockIdx.x * 4 + wid;
    float inv = 1.0f / fmaxf((float)cnt[g], 1.0f);
#pragma unroll
    for (int k = lane; k < 256; k += 64) prow[wid][k] = pooled[g * 256 + k] * inv;
    __syncthreads();
    float acc = fc1b[lane];
#pragma unroll 4
    for (int k = 0; k < 256; k++) acc += prow[wid][k] * fc1W[k * 64 + lane];
    zrow[wid][lane] = gelu_exact(acc);
    __syncthreads();
    float logit = fc2b[lane];
#pragma unroll 4
    for (int k = 0; k < 64; k++) logit += zrow[wid][k] * fc2W[k * 64 + lane];
    float mx = wave_max(logit);
    float se = wave_sum(__expf(logit - mx));
    out[g * NOUT + lane] = logit - mx - logf(se);
}

extern "C" void kernel_launch(void* const* d_in, const int* in_sizes, int n_in,
                              void* d_out, int out_size, void* d_ws, size_t ws_size,
                              hipStream_t stream) {
    const float* x     = (const float*)d_in[0];
    const int*   ei    = (const int*)d_in[1];
    const int*   batch = (const int*)d_in[2];
    const int*   gid   = (const int*)d_in[3];
    const float* gt    = (const float*)d_in[4];
    const float* inW   = (const float*)d_in[5];
    const float* inb   = (const float*)d_in[6];
    const float* inlng = (const float*)d_in[7];
    const float* inlnb = (const float*)d_in[8];
    const float* W0    = (const float*)d_in[9];
    const float* as0   = (const float*)d_in[10];
    const float* ad0   = (const float*)d_in[11];
    const float* b0    = (const float*)d_in[12];
    const float* ln0g  = (const float*)d_in[13];
    const float* ln0b  = (const float*)d_in[14];
    const float* W1    = (const float*)d_in[15];
    const float* as1   = (const float*)d_in[16];
    const float* ad1   = (const float*)d_in[17];
    const float* b1    = (const float*)d_in[18];
    const float* ln1g  = (const float*)d_in[19];
    const float* ln1b  = (const float*)d_in[20];
    const float* fc1W  = (const float*)d_in[21];
    const float* fc1b  = (const float*)d_in[22];
    const float* fc2W  = (const float*)d_in[23];
    const float* fc2b  = (const float*)d_in[24];
    float* out = (float*)d_out;

    char* ws = (char*)d_ws;
    size_t off = 0;
    auto alloc = [&](size_t bytes) {
        void* p = ws + off;
        off += (bytes + 255) / 256 * 256;
        return p;
    };
    unsigned int*   h08    = (unsigned int*)alloc((size_t)N_NODES * 16 * 4);
    unsigned short* agg0bf = (unsigned short*)alloc((size_t)N_NODES * 256 * 2);
    unsigned short* h1bf   = (unsigned short*)alloc((size_t)N_NODES * 256 * 2);
    unsigned int*   xl8    = (unsigned int*)alloc((size_t)N_NODES * 64 * 4);
    unsigned short* inWpk  = (unsigned short*)alloc((size_t)192 * 64 * 2);
    unsigned short* W0pk   = (unsigned short*)alloc((size_t)64 * 256 * 2);
    unsigned short* W1pk   = (unsigned short*)alloc((size_t)256 * 256 * 2);
    float* us     = (float*)alloc((size_t)256 * 4);
    float* ud     = (float*)alloc((size_t)256 * 4);
    float* als0   = (float*)alloc((size_t)N_NODES * 4 * 4);
    float* ald0   = (float*)alloc((size_t)N_NODES * 4 * 4);
    float* als1   = (float*)alloc((size_t)N_NODES * 4 * 4);
    float* ald1   = (float*)alloc((size_t)N_NODES * 4 * 4);
    int*   rowptr = (int*)alloc((size_t)(N_NODES + 1) * 4);
    int*   cursor = (int*)alloc((size_t)N_NODES * 4);
    int*   csr    = (int*)alloc((size_t)ETOT * 4);
    // zero-init region: pooled | cnt | deg contiguous -> one memset
    float* pooled = (float*)alloc((size_t)NGRAPH * 256 * 4);
    int*   cnt    = (int*)alloc((size_t)NGRAPH * 4);
    int*   deg    = (int*)alloc((size_t)N_NODES * 4);
    size_t zspan = ((char*)deg + (size_t)N_NODES * 4) - (char*)pooled;

    hipMemsetAsync(pooled, 0, zspan, stream);

    k_prep_all<<<EB + 369, 256, 0, stream>>>(ei, inW, W0, W1, as0, ad0, deg,
                                             inWpk, W0pk, W1pk, us, ud);
    k_scan<<<1, 1024, 0, stream>>>(deg, rowptr, cursor);
    k_fill<<<EB, 256, 0, stream>>>(ei, cursor, csr);

    k_proj_in_mma<<<(N_NODES + 63) / 64, 256, 0, stream>>>(x, gid, gt, inWpk, inb, inlng, inlnb,
                                                           us, ud, h08, als0, ald0);
    k_agg0<<<N_NODES / 2, 256, 0, stream>>>(rowptr, csr, h08, als0, ald0, agg0bf);
    k_postgemm0<<<(N_NODES + 63) / 64, 256, 0, stream>>>(agg0bf, W0pk, b0, ln0g, ln0b, h1bf);
    k_proj_mma<<<N_NODES / 16, 256, 0, stream>>>(h1bf, W1pk, as1, ad1, xl8, als1, ald1);
    k_agg1<<<N_NODES / 2, 256, 0, stream>>>(rowptr, csr, xl8, als1, ald1, b1, ln1g, ln1b,
                                            h1bf, batch, pooled, cnt);
    k_final<<<NGRAPH / 4, 256, 0, stream>>>(pooled, cnt, fc1W, fc1b, fc2W, fc2b, out);
}

// Round 13
// 361.071 us; speedup vs baseline: 1.3106x; 1.3106x over previous
//
#include <hip/hip_runtime.h>
#include <math.h>

#define N_NODES 50000
#define N_EDGES 800000
#define ETOT (N_EDGES + N_NODES)
#define EB ((ETOT + 255) / 256)
#define NSB ((N_NODES + 1023) / 1024)   // 49 scan blocks
#define F_IN 128
#define HD 64
#define NHEAD 4
#define HC 256
#define NGRAPH 512
#define NOUT 64
#define LN_EPS 1e-5f

typedef __attribute__((ext_vector_type(8))) short bf16x8;
typedef __attribute__((ext_vector_type(4))) float f32x4;
typedef __attribute__((ext_vector_type(2))) float f32x2;

__device__ __forceinline__ float wave_sum(float v) {
#pragma unroll
    for (int m = 1; m < 64; m <<= 1) v += __shfl_xor(v, m, 64);
    return v;
}
__device__ __forceinline__ float wave_max(float v) {
#pragma unroll
    for (int m = 1; m < 64; m <<= 1) v = fmaxf(v, __shfl_xor(v, m, 64));
    return v;
}
__device__ __forceinline__ float red16(float v) {
    v += __shfl_xor(v, 1, 64);
    v += __shfl_xor(v, 2, 64);
    v += __shfl_xor(v, 4, 64);
    v += __shfl_xor(v, 8, 64);
    return v;
}
__device__ __forceinline__ float gelu_exact(float x) {
    return 0.5f * x * (1.0f + erff(x * 0.70710678118654752f));
}
__device__ __forceinline__ unsigned short f2bf(float x) {
    unsigned int u = __float_as_uint(x);
    return (unsigned short)((u + 0x7fffu + ((u >> 16) & 1u)) >> 16);
}
__device__ __forceinline__ float bf2f(unsigned short u) {
    return __uint_as_float(((unsigned int)u) << 16);
}

// ---------------- merged: degree count + weight packing + u-vector prep ----------------
__global__ void k_prep_all(const int* __restrict__ ei, const float* __restrict__ inW,
                           const float* __restrict__ W0, const float* __restrict__ W1,
                           const float* __restrict__ as0, const float* __restrict__ ad0,
                           int* __restrict__ deg,
                           unsigned short* __restrict__ inWpk, unsigned short* __restrict__ W0pk,
                           unsigned short* __restrict__ W1pk, float* __restrict__ us,
                           float* __restrict__ ud) {
    int b = blockIdx.x;
    if (b < EB) {
        int t = b * 256 + threadIdx.x;
        if (t >= ETOT) return;
        int dst = (t < N_EDGES) ? ei[N_EDGES + t] : (t - N_EDGES);
        atomicAdd(deg + dst, 1);
        return;
    }
    b -= EB;
    if (b < 48) {
        int tid = b * 256 + threadIdx.x;
        int i = tid & 7, l = (tid >> 3) & 63, t2 = tid >> 9;
        int nb = t2 % 4, kt = t2 / 4;
        int k = kt * 32 + ((l >> 4) << 3) + i;
        int n = nb * 16 + (l & 15);
        inWpk[tid] = f2bf(inW[k * 64 + n]);
    } else if (b < 112) {
        int tid = (b - 48) * 256 + threadIdx.x;
        int i = tid & 7, l = (tid >> 3) & 63, t2 = tid >> 9;
        int nb = t2 % 16, kt = t2 / 16;
        int q = kt * 32 + ((l >> 4) << 3) + i;   // packed row position
        int k = 16 * (q & 3) + (q >> 2);         // canonical W0 row (pi perm)
        int n = nb * 16 + (l & 15);
        W0pk[tid] = f2bf(W0[k * 256 + n]);
    } else if (b < 368) {
        int tid = (b - 112) * 256 + threadIdx.x;
        int i = tid & 7, l = (tid >> 3) & 63, t2 = tid >> 9;
        int nb = t2 % 16, kt = t2 / 16;
        int k = kt * 32 + ((l >> 4) << 3) + i;
        int n = nb * 16 + (l & 15);
        W1pk[tid] = f2bf(W1[k * 256 + n]);
    } else {
        int t = threadIdx.x;
        int h = t >> 6, k2 = t & 63;
        float ss = 0.f, dd = 0.f;
        for (int c = 0; c < 64; c++) {
            float w = W0[k2 * 256 + h * 64 + c];
            ss += w * as0[h * 64 + c];
            dd += w * ad0[h * 64 + c];
        }
        us[t] = ss;
        ud[t] = dd;
    }
}

// ---------------- 3-phase parallel scan: coalesced, multi-block ----------------
// phase A: per-block inclusive scan of 1024-element slice + block total
__global__ void k_scan_a(const int* __restrict__ deg, int* __restrict__ tmp_incl,
                         int* __restrict__ bsum) {
    __shared__ int wsum[16];
    int b = blockIdx.x, tid = threadIdx.x, wid = tid >> 6, lane = tid & 63;
    int idx = b * 1024 + tid;
    int v = (idx < N_NODES) ? deg[idx] : 0;
    int incl = v;
#pragma unroll
    for (int off = 1; off < 64; off <<= 1) {
        int t = __shfl_up(incl, off, 64);
        if (lane >= off) incl += t;
    }
    if (lane == 63) wsum[wid] = incl;
    __syncthreads();
    if (wid == 0) {
        int wv = (lane < 16) ? wsum[lane] : 0;
        int wincl = wv;
#pragma unroll
        for (int off = 1; off < 16; off <<= 1) {
            int t = __shfl_up(wincl, off, 64);
            if (lane >= off) wincl += t;
        }
        if (lane < 16) wsum[lane] = wincl - wv;  // exclusive wave offset
        if (lane == 15) bsum[b] = wincl;         // block total
    }
    __syncthreads();
    incl += wsum[wid];
    if (idx < N_NODES) tmp_incl[idx] = incl;
}

// phase B: add block offsets, write rowptr/cursor (coalesced)
__global__ void k_scan_b(const int* __restrict__ deg, const int* __restrict__ tmp_incl,
                         const int* __restrict__ bsum, int* __restrict__ rowptr,
                         int* __restrict__ cursor) {
    __shared__ int boff_s;
    int b = blockIdx.x, tid = threadIdx.x;
    if (tid < 64) {
        int p = (tid < b) ? bsum[tid] : 0;  // NSB=49 <= 64 lanes
#pragma unroll
        for (int m = 1; m < 64; m <<= 1) p += __shfl_xor(p, m, 64);
        if (tid == 0) boff_s = p;
    }
    __syncthreads();
    int idx = b * 1024 + tid;
    if (idx < N_NODES) {
        int incl = tmp_incl[idx] + boff_s;
        rowptr[idx + 1] = incl;
        cursor[idx] = incl - deg[idx];
    }
    if (idx == 0) rowptr[0] = 0;
}

__global__ void k_fill(const int* __restrict__ ei, int* __restrict__ cursor,
                       int* __restrict__ csr) {
    int t = blockIdx.x * blockDim.x + threadIdx.x;
    if (t >= ETOT) return;
    int src, dst;
    if (t < N_EDGES) { src = ei[t]; dst = ei[N_EDGES + t]; }
    else             { src = t - N_EDGES; dst = src; }
    int p = atomicAdd(cursor + dst, 1);
    csr[p] = src;
}

// ---------------- input projection (MFMA), direct f32 reads, fp8 out, fused logits ----------------
__global__ void k_proj_in_mma(const float* __restrict__ x, const int* __restrict__ gid,
                              const float* __restrict__ gt,
                              const unsigned short* __restrict__ Wpk,
                              const float* __restrict__ inb, const float* __restrict__ lng,
                              const float* __restrict__ lnb, const float* __restrict__ us,
                              const float* __restrict__ ud, unsigned int* __restrict__ h08,
                              float* __restrict__ als0, float* __restrict__ ald0) {
    int wid = threadIdx.x >> 6, lane = threadIdx.x & 63;
    int m0 = blockIdx.x * 64 + wid * 16;
    if (m0 >= N_NODES) return;
    int g16 = lane >> 4, c16 = lane & 15;
    int row_a = m0 + c16;
    int g = gid[row_a];
    f32x4 acc[4] = {{0,0,0,0},{0,0,0,0},{0,0,0,0},{0,0,0,0}};
#pragma unroll
    for (int kt = 0; kt < 6; kt++) {
        const float* src = (kt < 4) ? (x + (size_t)row_a * F_IN + kt * 32 + g16 * 8)
                                    : (gt + (size_t)g * HD + (kt - 4) * 32 + g16 * 8);
        float4 f0 = *(const float4*)(src);
        float4 f1 = *(const float4*)(src + 4);
        bf16x8 a;
        a[0] = (short)f2bf(f0.x); a[1] = (short)f2bf(f0.y);
        a[2] = (short)f2bf(f0.z); a[3] = (short)f2bf(f0.w);
        a[4] = (short)f2bf(f1.x); a[5] = (short)f2bf(f1.y);
        a[6] = (short)f2bf(f1.z); a[7] = (short)f2bf(f1.w);
#pragma unroll
        for (int nt = 0; nt < 4; nt++) {
            bf16x8 b = *(const bf16x8*)(Wpk + (((kt * 4 + nt) * 64 + lane) << 3));
            acc[nt] = __builtin_amdgcn_mfma_f32_16x16x32_bf16(a, b, acc[nt], 0, 0, 0);
        }
    }
    float bv[4], gv[4], bb[4];
    float usl[4][4], udl[4][4];
#pragma unroll
    for (int nt = 0; nt < 4; nt++) {
        int c = nt * 16 + c16;
        bv[nt] = inb[c]; gv[nt] = lng[c]; bb[nt] = lnb[c];
#pragma unroll
        for (int h = 0; h < 4; h++) {
            usl[h][nt] = us[h * 64 + c];
            udl[h][nt] = ud[h * 64 + c];
        }
    }
#pragma unroll
    for (int j = 0; j < 4; j++) {
        float d[4], s = 0.f;
#pragma unroll
        for (int nt = 0; nt < 4; nt++) { d[nt] = acc[nt][j] + bv[nt]; s += d[nt]; }
        float mu = red16(s) * (1.0f / 64.0f);
        float v = 0.f;
#pragma unroll
        for (int nt = 0; nt < 4; nt++) { d[nt] -= mu; v += d[nt] * d[nt]; }
        float r = rsqrtf(red16(v) * (1.0f / 64.0f) + LN_EPS);
        int row = m0 + g16 * 4 + j;
        float y0 = gelu_exact(d[0] * r * gv[0] + bb[0]);
        float y1 = gelu_exact(d[1] * r * gv[1] + bb[1]);
        float y2 = gelu_exact(d[2] * r * gv[2] + bb[2]);
        float y3 = gelu_exact(d[3] * r * gv[3] + bb[3]);
        int u = __builtin_amdgcn_cvt_pk_fp8_f32(y0, y1, 0, false);
        u = __builtin_amdgcn_cvt_pk_fp8_f32(y2, y3, u, true);
        h08[(size_t)row * 16 + c16] = (unsigned int)u;
        float ps0 = y0 * usl[0][0] + y1 * usl[0][1] + y2 * usl[0][2] + y3 * usl[0][3];
        float ps1 = y0 * usl[1][0] + y1 * usl[1][1] + y2 * usl[1][2] + y3 * usl[1][3];
        float ps2 = y0 * usl[2][0] + y1 * usl[2][1] + y2 * usl[2][2] + y3 * usl[2][3];
        float ps3 = y0 * usl[3][0] + y1 * usl[3][1] + y2 * usl[3][2] + y3 * usl[3][3];
        float pd0 = y0 * udl[0][0] + y1 * udl[0][1] + y2 * udl[0][2] + y3 * udl[0][3];
        float pd1 = y0 * udl[1][0] + y1 * udl[1][1] + y2 * udl[1][2] + y3 * udl[1][3];
        float pd2 = y0 * udl[2][0] + y1 * udl[2][1] + y2 * udl[2][2] + y3 * udl[2][3];
        float pd3 = y0 * udl[3][0] + y1 * udl[3][1] + y2 * udl[3][2] + y3 * udl[3][3];
        ps0 = red16(ps0); ps1 = red16(ps1); ps2 = red16(ps2); ps3 = red16(ps3);
        pd0 = red16(pd0); pd1 = red16(pd1); pd2 = red16(pd2); pd3 = red16(pd3);
        if (c16 == 0) {
            float4 s4 = {ps0, ps1, ps2, ps3};
            float4 d4 = {pd0, pd1, pd2, pd3};
            ((float4*)als0)[row] = s4;
            ((float4*)ald0)[row] = d4;
        }
    }
}

// ---------------- layer-0 aggregation over fp8 h0 (64B/edge), single-pass, unroll-2 ----------------
__global__ void k_agg0(const int* __restrict__ rowptr, const int* __restrict__ csr,
                       const unsigned int* __restrict__ h08, const float* __restrict__ als,
                       const float* __restrict__ ald, unsigned short* __restrict__ aggbf) {
    __shared__ float4 lacc[2][64];
    __shared__ float lss[2][4];
    int wid = threadIdx.x >> 6, lane = threadIdx.x & 63;
    int nloc = wid >> 1, half = wid & 1;
    int node = blockIdx.x * 2 + nloc;
    int start = rowptr[node], end = rowptr[node + 1];
    int g = lane >> 4, l16 = lane & 15;
    float4 adv = ((const float4*)ald)[node];
    int cntE = end - start;
    int mid = start + ((cntE + 1) >> 1);
    int k0 = half ? mid : start;
    int k1 = half ? end : mid;
    float a00 = 0, a01 = 0, a02 = 0, a03 = 0;
    float a10 = 0, a11 = 0, a12 = 0, a13 = 0;
    float a20 = 0, a21 = 0, a22 = 0, a23 = 0;
    float a30 = 0, a31 = 0, a32 = 0, a33 = 0;
    float s0 = 0, s1 = 0, s2 = 0, s3 = 0;
    const float4* als4 = (const float4*)als;
    for (int kb = k0; kb < k1; kb += 8) {
        int eA = kb + g, eB = kb + 4 + g;
        int cA = (eA < k1) ? eA : (k1 - 1);
        int cB = (eB < k1) ? eB : (k1 - 1);
        int snA = csr[cA], snB = csr[cB];
        float4 avA = als4[snA], avB = als4[snB];
        unsigned int uA = h08[(size_t)snA * 16 + l16];
        unsigned int uB = h08[(size_t)snB * 16 + l16];
        float eA0 = avA.x + adv.x; eA0 = fmaxf(eA0, 0.2f * eA0);
        float eA1 = avA.y + adv.y; eA1 = fmaxf(eA1, 0.2f * eA1);
        float eA2 = avA.z + adv.z; eA2 = fmaxf(eA2, 0.2f * eA2);
        float eA3 = avA.w + adv.w; eA3 = fmaxf(eA3, 0.2f * eA3);
        float wA0 = __expf(eA0), wA1 = __expf(eA1), wA2 = __expf(eA2), wA3 = __expf(eA3);
        if (eA >= k1) { wA0 = 0.f; wA1 = 0.f; wA2 = 0.f; wA3 = 0.f; }
        f32x2 loA = __builtin_amdgcn_cvt_pk_f32_fp8((int)uA, false);
        f32x2 hiA = __builtin_amdgcn_cvt_pk_f32_fp8((int)uA, true);
        s0 += wA0; s1 += wA1; s2 += wA2; s3 += wA3;
        float x0 = loA.x, x1 = loA.y, x2 = hiA.x, x3 = hiA.y;
        a00 += wA0 * x0; a01 += wA0 * x1; a02 += wA0 * x2; a03 += wA0 * x3;
        a10 += wA1 * x0; a11 += wA1 * x1; a12 += wA1 * x2; a13 += wA1 * x3;
        a20 += wA2 * x0; a21 += wA2 * x1; a22 += wA2 * x2; a23 += wA2 * x3;
        a30 += wA3 * x0; a31 += wA3 * x1; a32 += wA3 * x2; a33 += wA3 * x3;
        float eB0 = avB.x + adv.x; eB0 = fmaxf(eB0, 0.2f * eB0);
        float eB1 = avB.y + adv.y; eB1 = fmaxf(eB1, 0.2f * eB1);
        float eB2 = avB.z + adv.z; eB2 = fmaxf(eB2, 0.2f * eB2);
        float eB3 = avB.w + adv.w; eB3 = fmaxf(eB3, 0.2f * eB3);
        float wB0 = __expf(eB0), wB1 = __expf(eB1), wB2 = __expf(eB2), wB3 = __expf(eB3);
        if (eB >= k1) { wB0 = 0.f; wB1 = 0.f; wB2 = 0.f; wB3 = 0.f; }
        f32x2 loB = __builtin_amdgcn_cvt_pk_f32_fp8((int)uB, false);
        f32x2 hiB = __builtin_amdgcn_cvt_pk_f32_fp8((int)uB, true);
        s0 += wB0; s1 += wB1; s2 += wB2; s3 += wB3;
        float z0 = loB.x, z1 = loB.y, z2 = hiB.x, z3 = hiB.y;
        a00 += wB0 * z0; a01 += wB0 * z1; a02 += wB0 * z2; a03 += wB0 * z3;
        a10 += wB1 * z0; a11 += wB1 * z1; a12 += wB1 * z2; a13 += wB1 * z3;
        a20 += wB2 * z0; a21 += wB2 * z1; a22 += wB2 * z2; a23 += wB2 * z3;
        a30 += wB3 * z0; a31 += wB3 * z1; a32 += wB3 * z2; a33 += wB3 * z3;
    }
#define RED2(v) v += __shfl_xor(v, 16, 64); v += __shfl_xor(v, 32, 64)
    RED2(a00); RED2(a01); RED2(a02); RED2(a03);
    RED2(a10); RED2(a11); RED2(a12); RED2(a13);
    RED2(a20); RED2(a21); RED2(a22); RED2(a23);
    RED2(a30); RED2(a31); RED2(a32); RED2(a33);
    RED2(s0);  RED2(s1);  RED2(s2);  RED2(s3);
#undef RED2
    if (half) {
        float o0 = (g == 0) ? a00 : (g == 1) ? a10 : (g == 2) ? a20 : a30;
        float o1 = (g == 0) ? a01 : (g == 1) ? a11 : (g == 2) ? a21 : a31;
        float o2 = (g == 0) ? a02 : (g == 1) ? a12 : (g == 2) ? a22 : a32;
        float o3 = (g == 0) ? a03 : (g == 1) ? a13 : (g == 2) ? a23 : a33;
        float4 o = {o0, o1, o2, o3};
        lacc[nloc][lane] = o;
        if (lane < 4) {
            float sv = (lane == 0) ? s0 : (lane == 1) ? s1 : (lane == 2) ? s2 : s3;
            lss[nloc][lane] = sv;
        }
    }
    __syncthreads();
    if (!half) {
        float4 p0 = lacc[nloc][0 + l16];
        float4 p1 = lacc[nloc][16 + l16];
        float4 p2 = lacc[nloc][32 + l16];
        float4 p3 = lacc[nloc][48 + l16];
        a00 += p0.x; a01 += p0.y; a02 += p0.z; a03 += p0.w;
        a10 += p1.x; a11 += p1.y; a12 += p1.z; a13 += p1.w;
        a20 += p2.x; a21 += p2.y; a22 += p2.z; a23 += p2.w;
        a30 += p3.x; a31 += p3.y; a32 += p3.z; a33 += p3.w;
        s0 += lss[nloc][0]; s1 += lss[nloc][1];
        s2 += lss[nloc][2]; s3 += lss[nloc][3];
        float o0 = (g == 0) ? a00 : (g == 1) ? a10 : (g == 2) ? a20 : a30;
        float o1 = (g == 0) ? a01 : (g == 1) ? a11 : (g == 2) ? a21 : a31;
        float o2 = (g == 0) ? a02 : (g == 1) ? a12 : (g == 2) ? a22 : a32;
        float o3 = (g == 0) ? a03 : (g == 1) ? a13 : (g == 2) ? a23 : a33;
        float sg = (g == 0) ? s0 : (g == 1) ? s1 : (g == 2) ? s2 : s3;
        float inv = 1.0f / (sg + 1e-16f);
        ushort4 o = {f2bf(o0 * inv), f2bf(o1 * inv), f2bf(o2 * inv), f2bf(o3 * inv)};
        ((ushort4*)aggbf)[(size_t)node * 64 + lane] = o;
    }
}

// ---------------- post-agg block-diagonal GEMM (64->256 per head) + bias + LN + GELU ----------------
__global__ void k_postgemm0(const unsigned short* __restrict__ A,
                            const unsigned short* __restrict__ Wpk,
                            const float* __restrict__ bias, const float* __restrict__ lng,
                            const float* __restrict__ lnb, unsigned short* __restrict__ h1bf) {
    int wid = threadIdx.x >> 6, lane = threadIdx.x & 63;
    int m0 = blockIdx.x * 64 + wid * 16;
    if (m0 >= N_NODES) return;
    int g16 = lane >> 4, c16 = lane & 15;
    f32x4 acc[16] = {};
#pragma unroll
    for (int h = 0; h < 4; h++) {
#pragma unroll
        for (int kt = 0; kt < 2; kt++) {
            bf16x8 a = *(const bf16x8*)(A + (size_t)(m0 + c16) * 256 + h * 64 + kt * 32 + g16 * 8);
#pragma unroll
            for (int nt = 0; nt < 4; nt++) {
                bf16x8 b = *(const bf16x8*)(Wpk + (((kt * 16 + h * 4 + nt) * 64 + lane) << 3));
                acc[h * 4 + nt] = __builtin_amdgcn_mfma_f32_16x16x32_bf16(a, b, acc[h * 4 + nt], 0, 0, 0);
            }
        }
    }
    float bv[16], gv[16], bb[16];
#pragma unroll
    for (int q = 0; q < 16; q++) {
        int c = q * 16 + c16;
        bv[q] = bias[c]; gv[q] = lng[c]; bb[q] = lnb[c];
    }
#pragma unroll
    for (int j = 0; j < 4; j++) {
        float d[16], ssum = 0.f;
#pragma unroll
        for (int q = 0; q < 16; q++) { d[q] = acc[q][j] + bv[q]; ssum += d[q]; }
        float mu = red16(ssum) * (1.0f / 256.0f);
        float v = 0.f;
#pragma unroll
        for (int q = 0; q < 16; q++) { d[q] -= mu; v += d[q] * d[q]; }
        float r = rsqrtf(red16(v) * (1.0f / 256.0f) + LN_EPS);
        int row = m0 + g16 * 4 + j;
#pragma unroll
        for (int q = 0; q < 16; q++) {
            float y = gelu_exact(d[q] * r * gv[q] + bb[q]);
            h1bf[(size_t)row * 256 + q * 16 + c16] = f2bf(y);
        }
    }
}

// ---------------- GAT projection (MFMA): xl(fp8, permuted) = A@W1, + layer-1 logits ----------------
__global__ void k_proj_mma(const unsigned short* __restrict__ A,
                           const unsigned short* __restrict__ Wpk,
                           const float* __restrict__ as_, const float* __restrict__ ad_,
                           unsigned int* __restrict__ xl8, float* __restrict__ als,
                           float* __restrict__ ald) {
    int wid = threadIdx.x >> 6, lane = threadIdx.x & 63;  // wid = head
    int m0 = blockIdx.x * 16;
    int g16 = lane >> 4, c16 = lane & 15;
    f32x4 acc[4] = {{0,0,0,0},{0,0,0,0},{0,0,0,0},{0,0,0,0}};
#pragma unroll
    for (int kt = 0; kt < 8; kt++) {
        bf16x8 a = *(const bf16x8*)(A + (size_t)(m0 + c16) * 256 + kt * 32 + g16 * 8);
#pragma unroll
        for (int nt = 0; nt < 4; nt++) {
            bf16x8 b = *(const bf16x8*)(Wpk + (((kt * 16 + wid * 4 + nt) * 64 + lane) << 3));
            acc[nt] = __builtin_amdgcn_mfma_f32_16x16x32_bf16(a, b, acc[nt], 0, 0, 0);
        }
    }
    float asv[4], adv[4];
#pragma unroll
    for (int nt = 0; nt < 4; nt++) {
        int c = wid * 64 + nt * 16 + c16;
        asv[nt] = as_[c]; adv[nt] = ad_[c];
    }
#pragma unroll
    for (int j = 0; j < 4; j++) {
        int row = m0 + g16 * 4 + j;
        float v0 = acc[0][j], v1 = acc[1][j], v2 = acc[2][j], v3 = acc[3][j];
        int u = __builtin_amdgcn_cvt_pk_fp8_f32(v0, v1, 0, false);
        u = __builtin_amdgcn_cvt_pk_fp8_f32(v2, v3, u, true);
        xl8[(size_t)row * 64 + wid * 16 + c16] = (unsigned int)u;
        float ps = v0 * asv[0] + v1 * asv[1] + v2 * asv[2] + v3 * asv[3];
        float pd = v0 * adv[0] + v1 * adv[1] + v2 * adv[2] + v3 * adv[3];
        ps = red16(ps); pd = red16(pd);
        if (c16 == 0) { als[row * 4 + wid] = ps; ald[row * 4 + wid] = pd; }
    }
}

// ---------------- layer-1 aggregation (256B/edge fp8), 2 waves/node, unroll-4, fused epilogue ----------------
__global__ void k_agg1(const int* __restrict__ rowptr, const int* __restrict__ csr,
                       const unsigned int* __restrict__ xl8, const float* __restrict__ als,
                       const float* __restrict__ ald, const float* __restrict__ bias,
                       const float* __restrict__ lng, const float* __restrict__ lnb,
                       const unsigned short* __restrict__ identity_bf,
                       const int* __restrict__ batch, float* __restrict__ pooled,
                       int* __restrict__ cnt) {
    __shared__ float4 lacc[2][64];
    __shared__ float lss[2][64];
    __shared__ float4 lyout[2][64];
    __shared__ int lbatch[2];
    int wid = threadIdx.x >> 6, lane = threadIdx.x & 63;
    int nloc = wid >> 1, half = wid & 1;
    int node = blockIdx.x * 2 + nloc;
    int start = rowptr[node], end = rowptr[node + 1];
    int head = lane >> 4, c16 = lane & 15;
    int fb = head * 64 + c16;
    float adh = ald[node * 4 + head];
    int cntE = end - start;
    int mid = start + ((cntE + 1) >> 1);
    int k0 = half ? mid : start;
    int k1 = half ? end : mid;
    float4 acc = {0.f, 0.f, 0.f, 0.f};
    float s = 0.f;
    int k = k0;
    for (; k + 4 <= k1; k += 4) {
        int sn0 = csr[k], sn1 = csr[k + 1], sn2 = csr[k + 2], sn3 = csr[k + 3];
        float e0 = als[sn0 * 4 + head] + adh;
        float e1 = als[sn1 * 4 + head] + adh;
        float e2 = als[sn2 * 4 + head] + adh;
        float e3 = als[sn3 * 4 + head] + adh;
        unsigned int u0 = xl8[(size_t)sn0 * 64 + lane];
        unsigned int u1 = xl8[(size_t)sn1 * 64 + lane];
        unsigned int u2 = xl8[(size_t)sn2 * 64 + lane];
        unsigned int u3 = xl8[(size_t)sn3 * 64 + lane];
        e0 = fmaxf(e0, 0.2f * e0); e1 = fmaxf(e1, 0.2f * e1);
        e2 = fmaxf(e2, 0.2f * e2); e3 = fmaxf(e3, 0.2f * e3);
        float a0 = __expf(e0), a1 = __expf(e1), a2 = __expf(e2), a3 = __expf(e3);
        s += a0 + a1 + a2 + a3;
        f32x2 lo0 = __builtin_amdgcn_cvt_pk_f32_fp8((int)u0, false);
        f32x2 hi0 = __builtin_amdgcn_cvt_pk_f32_fp8((int)u0, true);
        f32x2 lo1 = __builtin_amdgcn_cvt_pk_f32_fp8((int)u1, false);
        f32x2 hi1 = __builtin_amdgcn_cvt_pk_f32_fp8((int)u1, true);
        f32x2 lo2 = __builtin_amdgcn_cvt_pk_f32_fp8((int)u2, false);
        f32x2 hi2 = __builtin_amdgcn_cvt_pk_f32_fp8((int)u2, true);
        f32x2 lo3 = __builtin_amdgcn_cvt_pk_f32_fp8((int)u3, false);
        f32x2 hi3 = __builtin_amdgcn_cvt_pk_f32_fp8((int)u3, true);
        acc.x += a0 * lo0.x + a1 * lo1.x + a2 * lo2.x + a3 * lo3.x;
        acc.y += a0 * lo0.y + a1 * lo1.y + a2 * lo2.y + a3 * lo3.y;
        acc.z += a0 * hi0.x + a1 * hi1.x + a2 * hi2.x + a3 * hi3.x;
        acc.w += a0 * hi0.y + a1 * hi1.y + a2 * hi2.y + a3 * hi3.y;
    }
    for (; k < k1; k++) {
        int sn = csr[k];
        float e = als[sn * 4 + head] + adh;
        e = fmaxf(e, 0.2f * e);
        float a = __expf(e);
        s += a;
        unsigned int u = xl8[(size_t)sn * 64 + lane];
        f32x2 lo = __builtin_amdgcn_cvt_pk_f32_fp8((int)u, false);
        f32x2 hi = __builtin_amdgcn_cvt_pk_f32_fp8((int)u, true);
        acc.x += a * lo.x; acc.y += a * lo.y;
        acc.z += a * hi.x; acc.w += a * hi.y;
    }
    if (half) { lacc[nloc][lane] = acc; lss[nloc][lane] = s; }
    __syncthreads();
    if (!half) {
        float4 p = lacc[nloc][lane];
        acc.x += p.x; acc.y += p.y; acc.z += p.z; acc.w += p.w;
        s += lss[nloc][lane];
        float inv = 1.0f / (s + 1e-16f);
        acc.x = acc.x * inv + bias[fb];
        acc.y = acc.y * inv + bias[fb + 16];
        acc.z = acc.z * inv + bias[fb + 32];
        acc.w = acc.w * inv + bias[fb + 48];
        float mu = wave_sum(acc.x + acc.y + acc.z + acc.w) * (1.0f / 256.0f);
        float dx = acc.x - mu, dy = acc.y - mu, dz = acc.z - mu, dw = acc.w - mu;
        float var = wave_sum(dx * dx + dy * dy + dz * dz + dw * dw) * (1.0f / 256.0f);
        float r = rsqrtf(var + LN_EPS);
        float g0v = lng[fb], g1v = lng[fb + 16], g2v = lng[fb + 32], g3v = lng[fb + 48];
        float b0v = lnb[fb], b1v = lnb[fb + 16], b2v = lnb[fb + 32], b3v = lnb[fb + 48];
        const unsigned short* idp = identity_bf + (size_t)node * 256 + fb;
        float4 y;
        y.x = gelu_exact(dx * r * g0v + b0v) + bf2f(idp[0]);
        y.y = gelu_exact(dy * r * g1v + b1v) + bf2f(idp[16]);
        y.z = gelu_exact(dz * r * g2v + b2v) + bf2f(idp[32]);
        y.w = gelu_exact(dw * r * g3v + b3v) + bf2f(idp[48]);
        lyout[nloc][lane] = y;
        if (lane == 0) lbatch[nloc] = batch[node];
    }
    __syncthreads();
    if (wid == 0) {
        int g0 = lbatch[0], g1 = lbatch[1];
        float4 a = lyout[0][lane], b = lyout[1][lane];
        float* p0 = pooled + (size_t)g0 * 256 + fb;
        if (g0 == g1) {
            atomicAdd(p0 +  0, a.x + b.x); atomicAdd(p0 + 16, a.y + b.y);
            atomicAdd(p0 + 32, a.z + b.z); atomicAdd(p0 + 48, a.w + b.w);
            if (lane == 0) atomicAdd(cnt + g0, 2);
        } else {
            float* p1 = pooled + (size_t)g1 * 256 + fb;
            atomicAdd(p0 +  0, a.x); atomicAdd(p0 + 16, a.y);
            atomicAdd(p0 + 32, a.z); atomicAdd(p0 + 48, a.w);
            atomicAdd(p1 +  0, b.x); atomicAdd(p1 + 16, b.y);
            atomicAdd(p1 + 32, b.z); atomicAdd(p1 + 48, b.w);
            if (lane == 0) { atomicAdd(cnt + g0, 1); atomicAdd(cnt + g1, 1); }
        }
    }
}

// ---------------- pooled MLP + log_softmax: one wave per graph ----------------
__global__ void k_final(const float* __restrict__ pooled, const int* __restrict__ cnt,
                        const float* __restrict__ fc1W, const float* __restrict__ fc1b,
                        const float* __restrict__ fc2W, const float* __restrict__ fc2b,
                        float* __restrict__ out) {
    __shared__ float prow[4][256];
    __shared__ float zrow[4][64];
    int wid = threadIdx.x >> 6, lane = threadIdx.x & 63;
    int g = blockIdx.x * 4 + wid;
    float inv = 1.0f / fmaxf((float)cnt[g], 1.0f);
#pragma unroll
    for (int k = lane; k < 256; k += 64) prow[wid][k] = pooled[g * 256 + k] * inv;
    __syncthreads();
    float acc = fc1b[lane];
#pragma unroll 4
    for (int k = 0; k < 256; k++) acc += prow[wid][k] * fc1W[k * 64 + lane];
    zrow[wid][lane] = gelu_exact(acc);
    __syncthreads();
    float logit = fc2b[lane];
#pragma unroll 4
    for (int k = 0; k < 64; k++) logit += zrow[wid][k] * fc2W[k * 64 + lane];
    float mx = wave_max(logit);
    float se = wave_sum(__expf(logit - mx));
    out[g * NOUT + lane] = logit - mx - logf(se);
}

extern "C" void kernel_launch(void* const* d_in, const int* in_sizes, int n_in,
                              void* d_out, int out_size, void* d_ws, size_t ws_size,
                              hipStream_t stream) {
    const float* x     = (const float*)d_in[0];
    const int*   ei    = (const int*)d_in[1];
    const int*   batch = (const int*)d_in[2];
    const int*   gid   = (const int*)d_in[3];
    const float* gt    = (const float*)d_in[4];
    const float* inW   = (const float*)d_in[5];
    const float* inb   = (const float*)d_in[6];
    const float* inlng = (const float*)d_in[7];
    const float* inlnb = (const float*)d_in[8];
    const float* W0    = (const float*)d_in[9];
    const float* as0   = (const float*)d_in[10];
    const float* ad0   = (const float*)d_in[11];
    const float* b0    = (const float*)d_in[12];
    const float* ln0g  = (const float*)d_in[13];
    const float* ln0b  = (const float*)d_in[14];
    const float* W1    = (const float*)d_in[15];
    const float* as1   = (const float*)d_in[16];
    const float* ad1   = (const float*)d_in[17];
    const float* b1    = (const float*)d_in[18];
    const float* ln1g  = (const float*)d_in[19];
    const float* ln1b  = (const float*)d_in[20];
    const float* fc1W  = (const float*)d_in[21];
    const float* fc1b  = (const float*)d_in[22];
    const float* fc2W  = (const float*)d_in[23];
    const float* fc2b  = (const float*)d_in[24];
    float* out = (float*)d_out;

    char* ws = (char*)d_ws;
    size_t off = 0;
    auto alloc = [&](size_t bytes) {
        void* p = ws + off;
        off += (bytes + 255) / 256 * 256;
        return p;
    };
    unsigned int*   h08    = (unsigned int*)alloc((size_t)N_NODES * 16 * 4);
    unsigned short* agg0bf = (unsigned short*)alloc((size_t)N_NODES * 256 * 2);
    unsigned short* h1bf   = (unsigned short*)alloc((size_t)N_NODES * 256 * 2);
    unsigned int*   xl8    = (unsigned int*)alloc((size_t)N_NODES * 64 * 4);
    unsigned short* inWpk  = (unsigned short*)alloc((size_t)192 * 64 * 2);
    unsigned short* W0pk   = (unsigned short*)alloc((size_t)64 * 256 * 2);
    unsigned short* W1pk   = (unsigned short*)alloc((size_t)256 * 256 * 2);
    float* us     = (float*)alloc((size_t)256 * 4);
    float* ud     = (float*)alloc((size_t)256 * 4);
    float* als0   = (float*)alloc((size_t)N_NODES * 4 * 4);
    float* ald0   = (float*)alloc((size_t)N_NODES * 4 * 4);
    float* als1   = (float*)alloc((size_t)N_NODES * 4 * 4);
    float* ald1   = (float*)alloc((size_t)N_NODES * 4 * 4);
    int*   rowptr = (int*)alloc((size_t)(N_NODES + 1) * 4);
    int*   cursor = (int*)alloc((size_t)N_NODES * 4);
    int*   csr    = (int*)alloc((size_t)ETOT * 4);
    int*   tmpi   = (int*)alloc((size_t)N_NODES * 4);
    int*   bsum   = (int*)alloc((size_t)NSB * 4);
    // zero-init region: pooled | cnt | deg contiguous -> one memset
    float* pooled = (float*)alloc((size_t)NGRAPH * 256 * 4);
    int*   cnt    = (int*)alloc((size_t)NGRAPH * 4);
    int*   deg    = (int*)alloc((size_t)N_NODES * 4);
    size_t zspan = ((char*)deg + (size_t)N_NODES * 4) - (char*)pooled;

    hipMemsetAsync(pooled, 0, zspan, stream);

    k_prep_all<<<EB + 369, 256, 0, stream>>>(ei, inW, W0, W1, as0, ad0, deg,
                                             inWpk, W0pk, W1pk, us, ud);
    k_scan_a<<<NSB, 1024, 0, stream>>>(deg, tmpi, bsum);
    k_scan_b<<<NSB, 1024, 0, stream>>>(deg, tmpi, bsum, rowptr, cursor);
    k_fill<<<EB, 256, 0, stream>>>(ei, cursor, csr);

    k_proj_in_mma<<<(N_NODES + 63) / 64, 256, 0, stream>>>(x, gid, gt, inWpk, inb, inlng, inlnb,
                                                           us, ud, h08, als0, ald0);
    k_agg0<<<N_NODES / 2, 256, 0, stream>>>(rowptr, csr, h08, als0, ald0, agg0bf);
    k_postgemm0<<<(N_NODES + 63) / 64, 256, 0, stream>>>(agg0bf, W0pk, b0, ln0g, ln0b, h1bf);
    k_proj_mma<<<N_NODES / 16, 256, 0, stream>>>(h1bf, W1pk, as1, ad1, xl8, als1, ald1);
    k_agg1<<<N_NODES / 2, 256, 0, stream>>>(rowptr, csr, xl8, als1, ald1, b1, ln1g, ln1b,
                                            h1bf, batch, pooled, cnt);
    k_final<<<NGRAPH / 4, 256, 0, stream>>>(pooled, cnt, fc1W, fc1b, fc2W, fc2b, out);
}